// Round 1
// 2328.537 us; speedup vs baseline: 1.4303x; 1.4303x over previous
//
#include <hip/hip_runtime.h>

#define EPS 0.01f
#define TSTEPS 2048
#define BATCH 64

typedef _Float16 half8 __attribute__((ext_vector_type(8)));
typedef _Float16 half4 __attribute__((ext_vector_type(4)));
typedef float f32x4 __attribute__((ext_vector_type(4)));

// Workgroup barrier WITHOUT the vmcnt(0) drain the compiler emits for
// __syncthreads(). LDS visibility needs lgkmcnt(0) only; global loads
// (xu prefetch) and stores (h writeback) are lane-private and stay in
// flight across the barrier (AITER-style fine-grained pipelining).
#define LDS_BARRIER() asm volatile("s_waitcnt lgkmcnt(0)\n\ts_barrier" ::: "memory")

// ---------------------------------------------------------------------------
// prep_mc_pack: build Mc^T directly as f16 MFMA A-operand fragments.
// New 8-wave decomposition: wave w (0..7) owns 32 output cols 32w..32w+31.
// frag id f = (w*4 + mt)*8 + kk;  mt 0..1 = A-part (from B), mt 2..3 = W-part
// (from C), each 16-col tile at col 32w + 16*(mt&1).
// A-frag layout: lane l holds A[m=l&15][k=kk*32+(l>>4)*8+j], j=0..7, where
// A-operand element (c,k) = Mat[k][c], Mat = Src - 0.6*Src^T - 0.01I.
// ---------------------------------------------------------------------------
__global__ void prep_mc_pack(const float* __restrict__ Bm, const float* __restrict__ Cm,
                             _Float16* __restrict__ mcPack) {
    int f = blockIdx.x;       // 0..255
    int lane = threadIdx.x;   // 0..63
    int w = f >> 5;           // wave 0..7
    int mt = (f >> 3) & 3;    // 0..3
    int kk = f & 7;
    const float* Src = (mt < 2) ? Bm : Cm;
    int c = 32 * w + 16 * (mt & 1) + (lane & 15);
    int k0 = kk * 32 + (lane >> 4) * 8;
    long off = ((long)f * 64 + lane) * 8;
#pragma unroll
    for (int j = 0; j < 8; ++j) {
        int k = k0 + j;
        float diag = (k == c) ? 0.01f : 0.0f;
        float v = Src[(long)k * 256 + c] - 0.6f * Src[(long)c * 256 + k] - diag;
        mcPack[off + j] = (_Float16)v;
    }
}

// ---------------------------------------------------------------------------
// pack_u: U (256x256 fp32) -> f16 B-operand fragments for xu_gemm.
// ---------------------------------------------------------------------------
__global__ void pack_u(const float* __restrict__ U, _Float16* __restrict__ up) {
    int t = blockIdx.x * 64 + threadIdx.x;
    int lane = t & 63;
    int tile = t >> 6;      // kk*16 + nn
    int nn = tile & 15;
    int kk = tile >> 4;
    int krow = kk * 32 + (lane >> 4) * 8;
    int col = nn * 16 + (lane & 15);
    long off = (long)t * 8;
#pragma unroll
    for (int jj = 0; jj < 8; ++jj) {
        up[off + jj] = (_Float16)U[(krow + jj) * 256 + col];
    }
}

// ---------------------------------------------------------------------------
// xu_gemm: out[r][n] = sum_k x[r][k]*U[k][n] + bias[n]  (f16 MFMA, fp32 out)
// Writes into d_out; scan overwrites in place with h.
// ---------------------------------------------------------------------------
__global__ __launch_bounds__(256) void xu_gemm(const float* __restrict__ x,
                                               const _Float16* __restrict__ up,
                                               const float* __restrict__ bias,
                                               float* __restrict__ out) {
    int wave = threadIdx.x >> 6;
    int lane = threadIdx.x & 63;
    int m = lane & 15;
    int quad = lane >> 4;
    long row0 = (long)blockIdx.x * 64 + wave * 16;
    const float* xrow = x + (row0 + m) * 256 + quad * 8;

    f32x4 acc[16];
#pragma unroll
    for (int nn = 0; nn < 16; ++nn) acc[nn] = (f32x4){0.f, 0.f, 0.f, 0.f};

#pragma unroll
    for (int kk = 0; kk < 8; ++kk) {
        f32x4 xa = *(const f32x4*)(xrow + kk * 32);
        f32x4 xb = *(const f32x4*)(xrow + kk * 32 + 4);
        half8 af;
        af[0] = (_Float16)xa[0]; af[1] = (_Float16)xa[1];
        af[2] = (_Float16)xa[2]; af[3] = (_Float16)xa[3];
        af[4] = (_Float16)xb[0]; af[5] = (_Float16)xb[1];
        af[6] = (_Float16)xb[2]; af[7] = (_Float16)xb[3];
        const _Float16* ub = up + ((long)kk * 1024 + lane) * 8;
#pragma unroll
        for (int nn = 0; nn < 16; ++nn) {
            half8 bf = *(const half8*)(ub + (long)nn * 512);
            acc[nn] = __builtin_amdgcn_mfma_f32_16x16x32_f16(af, bf, acc[nn], 0, 0, 0);
        }
    }
#pragma unroll
    for (int nn = 0; nn < 16; ++nn) {
        int col = nn * 16 + m;
        float bv = bias[col];
#pragma unroll
        for (int i = 0; i < 4; ++i) {
            out[(row0 + quad * 4 + i) * 256 + col] = acc[nn][i] + bv;
        }
    }
}

// ---------------------------------------------------------------------------
// scan_kernel: grid=4 (16 batch rows each), 512 threads = 8 waves,
// 2 waves/SIMD (co-scheduling: one wave's tanh/elementwise overlaps the
// other's MFMAs — m114-style MFMA+VALU overlap).
// Wave w owns 32 output cols (2 A-tiles + 2 W-tiles); Mc fragments
// stationary (128 regs -> AGPRs); h double-buffered in LDS as f16 B-frags;
// xu read in-place from d_out (2-step prefetch) and overwritten with h_t.
// ---------------------------------------------------------------------------
__global__ __launch_bounds__(512, 2) void scan_kernel(const _Float16* __restrict__ mcPack,
                                                      float* __restrict__ io) {
    const int tid = threadIdx.x;
    const int w = tid >> 6;       // 0..7
    const int lane = tid & 63;
    const int m = lane & 15;
    const int q = lane >> 4;
    const int b0 = blockIdx.x * 16;

    // Stationary A-operand fragments: 4 M-tiles x 8 K-steps = 128 regs/lane.
    half8 mcf[4][8];
#pragma unroll
    for (int mt = 0; mt < 4; ++mt)
#pragma unroll
        for (int kk = 0; kk < 8; ++kk)
            mcf[mt][kk] = *(const half8*)(mcPack + (((long)(w * 4 + mt) * 8 + kk) * 64 + lane) * 8);

    __shared__ _Float16 hB[2][4096];  // 2 x 8KB double buffer, h^T as B-frags

    // zero buffer 0 (h0 = 0): 512 threads x 8 halfs
    {
        half8 z = (half8)(_Float16)0.0f;
        *(half8*)(&hB[0][tid * 8]) = z;
    }

    const int rdIdx = lane * 8;
    // wave w writes exactly kk-frag w: cols 32w..32w+31 map to k-range of frag w.
    const int wrIdx = 512 * w + 8 * m + 128 * (q >> 1) + 4 * (q & 1);

    // per-lane global pointer: row b0+m, col 32w+4q; +16*mt via imm offset.
    float* p = io + ((long)(b0 + m) * TSTEPS) * 256 + 32 * w + 4 * q;

    f32x4 hrow[2];
#pragma unroll
    for (int mt = 0; mt < 2; ++mt) hrow[mt] = (f32x4){0.f, 0.f, 0.f, 0.f};

    f32x4 xq[2][2];
#pragma unroll
    for (int mt = 0; mt < 2; ++mt) {
        xq[0][mt] = *(const f32x4*)(p + mt * 16);
        xq[1][mt] = *(const f32x4*)(p + 256 + mt * 16);
    }
    __syncthreads();

    auto step = [&](int t, const _Float16* hbR, _Float16* hbW, f32x4 (&xc)[2]) {
        // ---- MFMA phase: read full h as B-frags, 32 MFMAs (4 chains x 8) ----
        half8 hb[8];
#pragma unroll
        for (int kk = 0; kk < 8; ++kk)
            hb[kk] = *(const half8*)(hbR + kk * 512 + rdIdx);

        f32x4 acc[4];
#pragma unroll
        for (int mt = 0; mt < 4; ++mt) {
            acc[mt] = __builtin_amdgcn_mfma_f32_16x16x32_f16(mcf[mt][0], hb[0],
                                                             (f32x4){0.f, 0.f, 0.f, 0.f}, 0, 0, 0);
        }
#pragma unroll
        for (int kk = 1; kk < 8; ++kk)
#pragma unroll
            for (int mt = 0; mt < 4; ++mt)
                acc[mt] = __builtin_amdgcn_mfma_f32_16x16x32_f16(mcf[mt][kk], hb[kk], acc[mt], 0, 0, 0);

        // ---- elementwise: h += EPS*oa + EPS*tanh(ow + xu), all in regs ----
#pragma unroll
        for (int mt = 0; mt < 2; ++mt) {
            f32x4 oa = acc[mt];
            f32x4 ow = acc[mt + 2];
            f32x4 xv = xc[mt];
            f32x4 hn;
#pragma unroll
            for (int i = 0; i < 4; ++i) {
                float arg = ow[i] + xv[i];
                // tanh(x) = 1 - 2/(1+e^{2x});  e^{2x} = 2^{x*2*log2(e)}
                float e = __builtin_amdgcn_exp2f(arg * 2.8853900817779268f);
                float r = __builtin_amdgcn_rcpf(e + 1.0f);
                float th = fmaf(-2.0f, r, 1.0f);
                float v = fmaf(EPS, oa[i], hrow[mt][i]);
                hn[i] = fmaf(EPS, th, v);
            }
            hrow[mt] = hn;
            half4 h4;
#pragma unroll
            for (int i = 0; i < 4; ++i) h4[i] = (_Float16)hn[i];
            *(half4*)(hbW + wrIdx + mt * 256) = h4;  // next-step B-frags (LDS)
            *(f32x4*)(p + mt * 16) = hn;             // h_t -> global out (in place)
        }

        // ---- prefetch xu[t+2] (stays in flight across the barrier) ----
        if (t + 2 < TSTEPS) {
#pragma unroll
            for (int mt = 0; mt < 2; ++mt)
                xc[mt] = *(const f32x4*)(p + 512 + mt * 16);
        }
        p += 256;
        LDS_BARRIER();  // lgkmcnt(0)-only barrier: no vmcnt drain
    };

    for (int t = 0; t < TSTEPS; t += 2) {
        step(t, hB[0], hB[1], xq[0]);
        step(t + 1, hB[1], hB[0], xq[1]);
    }
}

extern "C" void kernel_launch(void* const* d_in, const int* in_sizes, int n_in,
                              void* d_out, int out_size, void* d_ws, size_t ws_size,
                              hipStream_t stream) {
    const float* x    = (const float*)d_in[0];
    const float* C    = (const float*)d_in[1];
    const float* Bm   = (const float*)d_in[2];
    const float* U    = (const float*)d_in[3];
    const float* bias = (const float*)d_in[4];
    float* out = (float*)d_out;

    _Float16* mcPack = (_Float16*)d_ws;                         // 256 KB
    _Float16* up     = (_Float16*)((char*)d_ws + 262144);       // 128 KB

    prep_mc_pack<<<256, 64, 0, stream>>>(Bm, C, mcPack);
    pack_u<<<128, 64, 0, stream>>>(U, up);
    xu_gemm<<<2048, 256, 0, stream>>>(x, up, bias, out);
    scan_kernel<<<4, 512, 0, stream>>>(mcPack, out);
}

// Round 2
// 2219.111 us; speedup vs baseline: 1.5008x; 1.0493x over previous
//
#include <hip/hip_runtime.h>

#define EPS 0.01f
#define TSTEPS 2048
#define BATCH 64
// 2*log2(e): exp(2x) = exp2(x * TWOLOG2E). W and xu are pre-scaled by this
// at pack time so the tanh argument arrives ready for v_exp_f32 (exp2).
#define TWOLOG2E 2.8853900817779268f

typedef _Float16 half8 __attribute__((ext_vector_type(8)));
typedef _Float16 half4 __attribute__((ext_vector_type(4)));
typedef float f32x4 __attribute__((ext_vector_type(4)));

// Workgroup barrier WITHOUT the vmcnt(0) drain the compiler emits for
// __syncthreads(). LDS visibility needs lgkmcnt(0) only; global loads
// (xu prefetch) and stores (h writeback) are lane-private and stay in
// flight across the barrier (AITER-style fine-grained pipelining).
#define LDS_BARRIER() asm volatile("s_waitcnt lgkmcnt(0)\n\ts_barrier" ::: "memory")

// ---------------------------------------------------------------------------
// prep_mc_pack: build Mc^T directly as f16 MFMA A-operand fragments.
// 8-wave decomposition: wave w (0..7) owns 32 output cols 32w..32w+31.
// frag id f = (w*4 + mt)*8 + kk;  mt 0..1 = A-part (from B), mt 2..3 = W-part
// (from C), each 16-col tile at col 32w + 16*(mt&1).
// W-part is PRE-SCALED by TWOLOG2E so the scan's exp2 needs no extra mul/add.
// A-frag layout: lane l holds A[m=l&15][k=kk*32+(l>>4)*8+j], j=0..7, where
// A-operand element (c,k) = Mat[k][c], Mat = Src - 0.6*Src^T - 0.01I.
// ---------------------------------------------------------------------------
__global__ void prep_mc_pack(const float* __restrict__ Bm, const float* __restrict__ Cm,
                             _Float16* __restrict__ mcPack) {
    int f = blockIdx.x;       // 0..255
    int lane = threadIdx.x;   // 0..63
    int w = f >> 5;           // wave 0..7
    int mt = (f >> 3) & 3;    // 0..3
    int kk = f & 7;
    const float* Src = (mt < 2) ? Bm : Cm;
    float scale = (mt < 2) ? 1.0f : TWOLOG2E;
    int c = 32 * w + 16 * (mt & 1) + (lane & 15);
    int k0 = kk * 32 + (lane >> 4) * 8;
    long off = ((long)f * 64 + lane) * 8;
#pragma unroll
    for (int j = 0; j < 8; ++j) {
        int k = k0 + j;
        float diag = (k == c) ? 0.01f : 0.0f;
        float v = scale * (Src[(long)k * 256 + c] - 0.6f * Src[(long)c * 256 + k] - diag);
        mcPack[off + j] = (_Float16)v;
    }
}

// ---------------------------------------------------------------------------
// pack_u: U (256x256 fp32) -> f16 B-operand fragments for xu_gemm.
// ---------------------------------------------------------------------------
__global__ void pack_u(const float* __restrict__ U, _Float16* __restrict__ up) {
    int t = blockIdx.x * 64 + threadIdx.x;
    int lane = t & 63;
    int tile = t >> 6;      // kk*16 + nn
    int nn = tile & 15;
    int kk = tile >> 4;
    int krow = kk * 32 + (lane >> 4) * 8;
    int col = nn * 16 + (lane & 15);
    long off = (long)t * 8;
#pragma unroll
    for (int jj = 0; jj < 8; ++jj) {
        up[off + jj] = (_Float16)U[(krow + jj) * 256 + col];
    }
}

// ---------------------------------------------------------------------------
// xu_gemm: out[r][n] = (sum_k x[r][k]*U[k][n] + bias[n]) * TWOLOG2E
// (pre-scaled tanh argument contribution). Writes into d_out; scan
// overwrites in place with h.
// ---------------------------------------------------------------------------
__global__ __launch_bounds__(256) void xu_gemm(const float* __restrict__ x,
                                               const _Float16* __restrict__ up,
                                               const float* __restrict__ bias,
                                               float* __restrict__ out) {
    int wave = threadIdx.x >> 6;
    int lane = threadIdx.x & 63;
    int m = lane & 15;
    int quad = lane >> 4;
    long row0 = (long)blockIdx.x * 64 + wave * 16;
    const float* xrow = x + (row0 + m) * 256 + quad * 8;

    f32x4 acc[16];
#pragma unroll
    for (int nn = 0; nn < 16; ++nn) acc[nn] = (f32x4){0.f, 0.f, 0.f, 0.f};

#pragma unroll
    for (int kk = 0; kk < 8; ++kk) {
        f32x4 xa = *(const f32x4*)(xrow + kk * 32);
        f32x4 xb = *(const f32x4*)(xrow + kk * 32 + 4);
        half8 af;
        af[0] = (_Float16)xa[0]; af[1] = (_Float16)xa[1];
        af[2] = (_Float16)xa[2]; af[3] = (_Float16)xa[3];
        af[4] = (_Float16)xb[0]; af[5] = (_Float16)xb[1];
        af[6] = (_Float16)xb[2]; af[7] = (_Float16)xb[3];
        const _Float16* ub = up + ((long)kk * 1024 + lane) * 8;
#pragma unroll
        for (int nn = 0; nn < 16; ++nn) {
            half8 bf = *(const half8*)(ub + (long)nn * 512);
            acc[nn] = __builtin_amdgcn_mfma_f32_16x16x32_f16(af, bf, acc[nn], 0, 0, 0);
        }
    }
#pragma unroll
    for (int nn = 0; nn < 16; ++nn) {
        int col = nn * 16 + m;
        float bv = bias[col];
#pragma unroll
        for (int i = 0; i < 4; ++i) {
            out[(row0 + quad * 4 + i) * 256 + col] = (acc[nn][i] + bv) * TWOLOG2E;
        }
    }
}

// ---------------------------------------------------------------------------
// scan_kernel: grid=4 (16 batch rows each), 512 threads = 8 waves,
// 2 waves/SIMD. Wave w owns 32 output cols (2 A-tiles + 2 W-tiles);
// Mc fragments stationary (128 regs -> AGPRs); h double-buffered in LDS as
// f16 B-frags; xu read in-place from d_out (2-step prefetch, pre-scaled by
// TWOLOG2E) and overwritten with h_t.
//
// Elementwise folding: A-chains are C-initialized with hs = h/EPS (own cols,
// in regs), W-chains with the pre-scaled xu. Then per element:
//   e  = exp2(accW)            (accW = 2*log2e*(h@W + xu))
//   r  = rcp(e + 1)
//   hs' = accA + 1 - 2r        (= h/EPS + h@A + tanh)
//   h  = EPS * hs'
// — 2 trans + 3 VALU/elem, vs 2 trans + 6 VALU before.
// Chains are issued as two independent (A,W) tile pairs; EW0 depends only on
// pair 0 so its VALU ops overlap pair 1's MFMA pipe drain.
// ---------------------------------------------------------------------------
__global__ __launch_bounds__(512, 2) void scan_kernel(const _Float16* __restrict__ mcPack,
                                                      float* __restrict__ io) {
    const int tid = threadIdx.x;
    const int w = tid >> 6;       // 0..7
    const int lane = tid & 63;
    const int m = lane & 15;
    const int q = lane >> 4;
    const int b0 = blockIdx.x * 16;

    // Stationary A-operand fragments: 4 M-tiles x 8 K-steps = 128 regs/lane.
    half8 mcf[4][8];
#pragma unroll
    for (int mt = 0; mt < 4; ++mt)
#pragma unroll
        for (int kk = 0; kk < 8; ++kk)
            mcf[mt][kk] = *(const half8*)(mcPack + (((long)(w * 4 + mt) * 8 + kk) * 64 + lane) * 8);

    __shared__ _Float16 hB[2][4096];  // 2 x 8KB double buffer, h^T as B-frags

    // zero buffer 0 (h0 = 0): 512 threads x 8 halfs
    {
        half8 z = (half8)(_Float16)0.0f;
        *(half8*)(&hB[0][tid * 8]) = z;
    }

    const int rdIdx = lane * 8;
    const int wrIdx = 512 * w + 8 * m + 128 * (q >> 1) + 4 * (q & 1);

    // per-lane global pointer: row b0+m, col 32w+4q; +16*mt via imm offset.
    float* p = io + ((long)(b0 + m) * TSTEPS) * 256 + 32 * w + 4 * q;

    // hs = h/EPS for this lane's own output elements (acc layout), starts 0.
    f32x4 hs[2];
    hs[0] = (f32x4){0.f, 0.f, 0.f, 0.f};
    hs[1] = (f32x4){0.f, 0.f, 0.f, 0.f};

    f32x4 xq[2][2];
#pragma unroll
    for (int mt = 0; mt < 2; ++mt) {
        xq[0][mt] = *(const f32x4*)(p + mt * 16);
        xq[1][mt] = *(const f32x4*)(p + 256 + mt * 16);
    }
    __syncthreads();

    auto step = [&](int t, const _Float16* hbR, _Float16* hbW, f32x4 (&xc)[2]) {
        // ---- read full h as B-frags ----
        half8 hb[8];
#pragma unroll
        for (int kk = 0; kk < 8; ++kk)
            hb[kk] = *(const half8*)(hbR + kk * 512 + rdIdx);

        // ---- tile pair 0: A chain (mt=0, C-init hs0), W chain (mt=2, C-init xu0)
        f32x4 aA = __builtin_amdgcn_mfma_f32_16x16x32_f16(mcf[0][0], hb[0], hs[0], 0, 0, 0);
        f32x4 aW = __builtin_amdgcn_mfma_f32_16x16x32_f16(mcf[2][0], hb[0], xc[0], 0, 0, 0);
#pragma unroll
        for (int kk = 1; kk < 8; ++kk) {
            aA = __builtin_amdgcn_mfma_f32_16x16x32_f16(mcf[0][kk], hb[kk], aA, 0, 0, 0);
            aW = __builtin_amdgcn_mfma_f32_16x16x32_f16(mcf[2][kk], hb[kk], aW, 0, 0, 0);
        }
        // ---- tile pair 1: issued before EW0 so EW0's VALU hides their drain
        f32x4 bA = __builtin_amdgcn_mfma_f32_16x16x32_f16(mcf[1][0], hb[0], hs[1], 0, 0, 0);
        f32x4 bW = __builtin_amdgcn_mfma_f32_16x16x32_f16(mcf[3][0], hb[0], xc[1], 0, 0, 0);
#pragma unroll
        for (int kk = 1; kk < 8; ++kk) {
            bA = __builtin_amdgcn_mfma_f32_16x16x32_f16(mcf[1][kk], hb[kk], bA, 0, 0, 0);
            bW = __builtin_amdgcn_mfma_f32_16x16x32_f16(mcf[3][kk], hb[kk], bW, 0, 0, 0);
        }

        // ---- EW tile 0 (depends only on aA/aW) ----
        {
            f32x4 hn;
#pragma unroll
            for (int i = 0; i < 4; ++i) {
                float e = __builtin_amdgcn_exp2f(aW[i]);
                float r = __builtin_amdgcn_rcpf(e + 1.0f);
                float hsv = fmaf(-2.0f, r, aA[i] + 1.0f);
                hs[0][i] = hsv;
                hn[i] = EPS * hsv;
            }
            half4 h4;
#pragma unroll
            for (int i = 0; i < 4; ++i) h4[i] = (_Float16)hn[i];
            *(half4*)(hbW + wrIdx) = h4;
            *(f32x4*)(p) = hn;
        }
        // ---- EW tile 1 ----
        {
            f32x4 hn;
#pragma unroll
            for (int i = 0; i < 4; ++i) {
                float e = __builtin_amdgcn_exp2f(bW[i]);
                float r = __builtin_amdgcn_rcpf(e + 1.0f);
                float hsv = fmaf(-2.0f, r, bA[i] + 1.0f);
                hs[1][i] = hsv;
                hn[i] = EPS * hsv;
            }
            half4 h4;
#pragma unroll
            for (int i = 0; i < 4; ++i) h4[i] = (_Float16)hn[i];
            *(half4*)(hbW + wrIdx + 256) = h4;
            *(f32x4*)(p + 16) = hn;
        }

        // ---- prefetch xu[t+2] (stays in flight across the barrier) ----
        if (t + 2 < TSTEPS) {
#pragma unroll
            for (int mt = 0; mt < 2; ++mt)
                xc[mt] = *(const f32x4*)(p + 512 + mt * 16);
        }
        p += 256;
        LDS_BARRIER();  // lgkmcnt(0)-only barrier: no vmcnt drain
    };

    for (int t = 0; t < TSTEPS; t += 2) {
        step(t, hB[0], hB[1], xq[0]);
        step(t + 1, hB[1], hB[0], xq[1]);
    }
}

extern "C" void kernel_launch(void* const* d_in, const int* in_sizes, int n_in,
                              void* d_out, int out_size, void* d_ws, size_t ws_size,
                              hipStream_t stream) {
    const float* x    = (const float*)d_in[0];
    const float* C    = (const float*)d_in[1];
    const float* Bm   = (const float*)d_in[2];
    const float* U    = (const float*)d_in[3];
    const float* bias = (const float*)d_in[4];
    float* out = (float*)d_out;

    _Float16* mcPack = (_Float16*)d_ws;                         // 256 KB
    _Float16* up     = (_Float16*)((char*)d_ws + 262144);       // 128 KB

    prep_mc_pack<<<256, 64, 0, stream>>>(Bm, C, mcPack);
    pack_u<<<128, 64, 0, stream>>>(U, up);
    xu_gemm<<<2048, 256, 0, stream>>>(x, up, bias, out);
    scan_kernel<<<4, 512, 0, stream>>>(mcPack, out);
}